// Round 1
// baseline (129.333 us; speedup 1.0000x reference)
//
#include <hip/hip_runtime.h>

// Quantum conv circuit, 16 qubits, batch 16.
// State: float2[16][65536] in d_ws (needs 8 MB + 16 KB of workspace).
// Bit convention: wire w <-> flat-index bit p = 15-w (axis 1 varies slowest).
//
// Gate table (60 gates, 8 floats each) + coupling table (60 * (cos,sin)) at d_ws[0];
// gate order: L1d0 j0..15 | L1d1 | L2d0 j0..7 | L2d1 | L3d0 j0..3 | L3d1 | L4d0 j0..1 | L4d1.

#define DEV __device__ __forceinline__

__device__ static const unsigned char G_CP[60] = {
  15,14,13,12,11,10,9,8,7,6,5,4,3,2,1,0,
  15,14,13,12,11,10,9,8,7,6,5,4,3,2,1,0,
  15,13,11,9,7,5,3,1,
  15,13,11,9,7,5,3,1,
  15,11,7,3,
  15,11,7,3,
  15,7,
  15,7
};
__device__ static const unsigned char G_CQ[60] = {
  14,13,12,11,10,9,8,7,6,5,4,3,2,1,0,15,
  14,13,12,11,10,9,8,7,6,5,4,3,2,1,0,15,
  13,11,9,7,5,3,1,15,
  13,11,9,7,5,3,1,15,
  11,7,3,15,
  11,7,3,15,
  7,15,
  7,15
};

DEV float2 F2(float x, float y){ float2 r; r.x = x; r.y = y; return r; }
DEV float2 cmulf(float2 a, float2 b){ return F2(a.x*b.x - a.y*b.y, a.x*b.y + a.y*b.x); }
// XOR swizzle on the low 4 bits of a float2 LDS slot index (bank-pair = slot%16)
DEV int swz(int j){ return j ^ ((j>>4)&15) ^ ((j>>8)&15); }

// Apply 2x2 unitary on register-slot bit B of a[16]. g = 8 floats (u00,u01,u10,u11).
template<int B>
DEV void gate(float2* a, const float* __restrict__ g){
  float2 u00=F2(g[0],g[1]), u01=F2(g[2],g[3]), u10=F2(g[4],g[5]), u11=F2(g[6],g[7]);
  #pragma unroll
  for (int m=0; m<8; m++){
    int i0 = ((m>>B)<<(B+1)) | (m & ((1<<B)-1));
    int i1 = i0 | (1<<B);
    float2 x0=a[i0], x1=a[i1];
    a[i0] = F2(u00.x*x0.x - u00.y*x0.y + u01.x*x1.x - u01.y*x1.y,
               u00.x*x0.y + u00.y*x0.x + u01.x*x1.y + u01.y*x1.x);
    a[i1] = F2(u10.x*x0.x - u10.y*x0.y + u11.x*x1.x - u11.y*x1.y,
               u10.x*x0.y + u10.y*x0.x + u11.x*x1.y + u11.y*x1.x);
  }
}

// CNOT with control slot-bit CB, target slot-bit TB (in-register permutation).
template<int CB,int TB>
DEV void cnotg(float2* a){
  #pragma unroll
  for (int r=0; r<16; r++){
    if ( ((r>>CB)&1)==1 && ((r>>TB)&1)==0 ){
      float2 tmp = a[r]; a[r] = a[r | (1<<TB)]; a[r | (1<<TB)] = tmp;
    }
  }
}

// RZZ diagonal round: couplings [C0, C0+N). Ib = global index with reg bits = 0.
// M0..M3 = global-bit masks of register slot bits 0..3 (compile-time).
// factor per coupling = (c, +s) if bits differ else (c, -s), c=cos(th/2), s=sin(th/2).
template<int C0,int N,unsigned M0,unsigned M1,unsigned M2,unsigned M3>
DEV void diag(float2* a, const float* __restrict__ tbl, unsigned Ib){
  const unsigned regmask = M0|M1|M2|M3;
  float2 F0 = F2(1.f, 0.f);
  #pragma unroll
  for (int k=0; k<N; k++){
    const int p = G_CP[C0+k], q = G_CQ[C0+k];
    if ( !(((1u<<p)|(1u<<q)) & regmask) ){
      float c = tbl[480 + 2*(C0+k)], s = tbl[481 + 2*(C0+k)];
      unsigned x = ((Ib>>p) ^ (Ib>>q)) & 1u;
      F0 = cmulf(F0, F2(c, x ? s : -s));
    }
  }
  #pragma unroll
  for (int r=0; r<16; r++){
    unsigned Ir = Ib ^ ((r&1)?M0:0u) ^ ((r&2)?M1:0u) ^ ((r&4)?M2:0u) ^ ((r&8)?M3:0u);
    float2 ph = F0;
    #pragma unroll
    for (int k=0; k<N; k++){
      const int p = G_CP[C0+k], q = G_CQ[C0+k];
      if ( ((1u<<p)|(1u<<q)) & regmask ){
        float c = tbl[480 + 2*(C0+k)], s = tbl[481 + 2*(C0+k)];
        unsigned x = ((Ir>>p) ^ (Ir>>q)) & 1u;
        ph = cmulf(ph, F2(c, x ? s : -s));
      }
    }
    a[r] = cmulf(a[r], ph);
  }
}

// ---------- setup: gate matrices U = RX(t2)*RZ(t1)*RX(t0) in double, + coupling cos/sin ----------
__global__ void k_setup(const float* __restrict__ p0, const float* __restrict__ p1,
                        const float* __restrict__ p2, const float* __restrict__ p3,
                        float* __restrict__ tbl){
  int g = threadIdx.x;
  if (g >= 60) return;
  int d, j, n; const float* P;
  if (g < 32)      { n=16; d=(g>>4)&1; j=g&15; P=p0; }
  else if (g < 48) { n=8;  d=(g>>3)&1; j=g&7;  P=p1; }
  else if (g < 56) { n=4;  d=(g>>2)&1; j=g&3;  P=p2; }
  else             { n=2;  d=(g>>1)&1; j=g&1;  P=p3; }
  int base = 4*j + 4*n*d;
  double th0 = P[base+0], th1 = P[base+1], th2 = P[base+2], th3 = P[base+3];
  double c0 = cos(th0*0.5), s0 = sin(th0*0.5);
  double ca = cos(th1*0.5), sa = sin(th1*0.5);
  double c2 = cos(th2*0.5), s2 = sin(th2*0.5);
  // B = RZ(th1)*RX(th0)
  double B00r =  ca*c0, B00i = -sa*c0;
  double B01r = -sa*s0, B01i = -ca*s0;
  double B10r =  sa*s0, B10i = -ca*s0;
  double B11r =  ca*c0, B11i =  sa*c0;
  // U = RX(th2)*B ;  (0,-s2)*(x,y) = (s2*y, -s2*x)
  double U00r = c2*B00r + s2*B10i, U00i = c2*B00i - s2*B10r;
  double U01r = c2*B01r + s2*B11i, U01i = c2*B01i - s2*B11r;
  double U10r = s2*B00i + c2*B10r, U10i = -s2*B00r + c2*B10i;
  double U11r = s2*B01i + c2*B11r, U11i = -s2*B01r + c2*B11i;
  float* o = tbl + g*8;
  o[0]=(float)U00r; o[1]=(float)U00i; o[2]=(float)U01r; o[3]=(float)U01i;
  o[4]=(float)U10r; o[5]=(float)U10i; o[6]=(float)U11r; o[7]=(float)U11i;
  tbl[480 + 2*g] = (float)cos(th3*0.5);
  tbl[481 + 2*g] = (float)sin(th3*0.5);
}

// ---------- pass 1: L1d0 U on bits 0..11. inner j = g bits 0..11, outer o = g bits 12..15 ----------
__global__ __launch_bounds__(256) void k_pass1(const float* __restrict__ xre, const float* __restrict__ xim,
                                               const float* __restrict__ tbl, float2* __restrict__ st){
  const int t = threadIdx.x;
  const int batch = blockIdx.x >> 4, o = blockIdx.x & 15;
  const unsigned hi = ((unsigned)batch<<16) | ((unsigned)o<<12);
  __shared__ float2 lds[2][4096];
  float2 a[16];
  // Stage 1: reg slots -> g{0,1,10,11}; j = (r&3) | (t<<2) | ((r>>2)<<10)
  #pragma unroll
  for (int rh=0; rh<4; rh++){
    unsigned I = hi | ((unsigned)t<<2) | ((unsigned)rh<<10);
    float4 re = *(const float4*)(xre + I);
    float4 im = *(const float4*)(xim + I);
    a[rh*4+0]=F2(re.x,im.x); a[rh*4+1]=F2(re.y,im.y);
    a[rh*4+2]=F2(re.z,im.z); a[rh*4+3]=F2(re.w,im.w);
  }
  gate<0>(a, tbl+15*8); gate<1>(a, tbl+14*8); gate<2>(a, tbl+5*8); gate<3>(a, tbl+4*8);
  #pragma unroll
  for (int r=0;r<16;r++){ int j = (r&3) | (t<<2) | ((r>>2)<<10); lds[0][swz(j)] = a[r]; }
  __syncthreads();
  // Stage 2: reg -> g{2,3,4,5}; j = (t&3) | (r<<2) | ((t>>2)<<6)
  #pragma unroll
  for (int r=0;r<16;r++){ int j = (t&3) | (r<<2) | ((t>>2)<<6); a[r] = lds[0][swz(j)]; }
  gate<0>(a, tbl+13*8); gate<1>(a, tbl+12*8); gate<2>(a, tbl+11*8); gate<3>(a, tbl+10*8);
  #pragma unroll
  for (int r=0;r<16;r++){ int j = (t&3) | (r<<2) | ((t>>2)<<6); lds[1][swz(j)] = a[r]; }
  __syncthreads();
  // Stage 3: reg -> g{6,7,8,9}; j = (t&63) | (r<<6) | ((t>>6)<<10)
  #pragma unroll
  for (int r=0;r<16;r++){ int j = (t&63) | (r<<6) | ((t>>6)<<10); a[r] = lds[1][swz(j)]; }
  gate<0>(a, tbl+9*8); gate<1>(a, tbl+8*8); gate<2>(a, tbl+7*8); gate<3>(a, tbl+6*8);
  #pragma unroll
  for (int r=0;r<16;r++){ int j = (t&63) | (r<<6) | ((t>>6)<<10); st[hi | j] = a[r]; }
}

// ---------- pass 2: L1d0 U bits 12..15, D0, L1d1 U on bits {0..5,10..15}. outer = g bits 6..9 ----------
__global__ __launch_bounds__(256) void k_pass2(const float* __restrict__ tbl, float2* __restrict__ st){
  const int t = threadIdx.x;
  const int batch = blockIdx.x >> 4, o = blockIdx.x & 15;
  const unsigned bb = (unsigned)batch<<16;
  __shared__ float2 lds[2][4096];
  float2 a[16];
  // I(j) = (j&63) | (o<<6) | ((j>>6)<<10) | bb
  // Stage 1: reg = j{8..11} -> g{12..15}; j = t | (r<<8)
  #pragma unroll
  for (int r=0;r<16;r++){
    unsigned I = (unsigned)(t&63) | ((unsigned)o<<6) | (((unsigned)(t>>6)&3u)<<10) | ((unsigned)r<<12) | bb;
    a[r] = st[I];
  }
  gate<0>(a, tbl+3*8); gate<1>(a, tbl+2*8); gate<2>(a, tbl+1*8); gate<3>(a, tbl+0*8);
  {
    unsigned Ib = (unsigned)(t&63) | ((unsigned)o<<6) | (((unsigned)(t>>6)&3u)<<10);
    diag<0,16, (1u<<12),(1u<<13),(1u<<14),(1u<<15)>(a, tbl, Ib);
  }
  gate<0>(a, tbl+19*8); gate<1>(a, tbl+18*8); gate<2>(a, tbl+17*8); gate<3>(a, tbl+16*8);
  #pragma unroll
  for (int r=0;r<16;r++){ int j = t | (r<<8); lds[0][swz(j)] = a[r]; }
  __syncthreads();
  // Stage 2: reg = j{0..3} -> g{0..3}; j = r | (t<<4)
  #pragma unroll
  for (int r=0;r<16;r++){ int j = r | (t<<4); a[r] = lds[0][swz(j)]; }
  gate<0>(a, tbl+31*8); gate<1>(a, tbl+30*8); gate<2>(a, tbl+29*8); gate<3>(a, tbl+28*8);
  #pragma unroll
  for (int r=0;r<16;r++){ int j = r | (t<<4); lds[1][swz(j)] = a[r]; }
  __syncthreads();
  // Stage 3: reg = j{4..7} -> g{4,5,10,11}; j = (t&15) | (r<<4) | ((t>>4)<<8)
  #pragma unroll
  for (int r=0;r<16;r++){ int j = (t&15) | (r<<4) | ((t>>4)<<8); a[r] = lds[1][swz(j)]; }
  gate<0>(a, tbl+27*8); gate<1>(a, tbl+26*8); gate<2>(a, tbl+21*8); gate<3>(a, tbl+20*8);
  #pragma unroll
  for (int r=0;r<16;r++){
    int j = (t&15) | (r<<4) | ((t>>4)<<8);
    unsigned I = (unsigned)(j&63) | ((unsigned)o<<6) | (((unsigned)j>>6)<<10) | bb;
    st[I] = a[r];
  }
}

// ---------- pass 3: L1d1 U on bits 6..9, then D1. inner = g bits 0..11, outer = g bits 12..15 ----------
__global__ __launch_bounds__(256) void k_pass3(const float* __restrict__ tbl, float2* __restrict__ st){
  const int t = threadIdx.x;
  const int batch = blockIdx.x >> 4, o = blockIdx.x & 15;
  const unsigned hi = ((unsigned)batch<<16) | ((unsigned)o<<12);
  float2 a[16];
  #pragma unroll
  for (int r=0;r<16;r++){ int j = (t&63) | (r<<6) | ((t>>6)<<10); a[r] = st[hi | j]; }
  gate<0>(a, tbl+25*8); gate<1>(a, tbl+24*8); gate<2>(a, tbl+23*8); gate<3>(a, tbl+22*8);
  {
    unsigned Ib = ((unsigned)o<<12) | (unsigned)(t&63) | (((unsigned)t>>6)<<10);
    diag<16,16, (1u<<6),(1u<<7),(1u<<8),(1u<<9)>(a, tbl, Ib);
  }
  #pragma unroll
  for (int r=0;r<16;r++){ int j = (t&63) | (r<<6) | ((t>>6)<<10); st[hi | j] = a[r]; }
}

// ---------- pass 4: sigma1 (fused load), layers 2..4, measurement ----------
// inner: j0..7 -> g0..7, j8->g9, j9->g11, j10->g13, j11->g15 ; outer o -> g{8,10,12,14}
__global__ __launch_bounds__(256) void k_pass4(const float* __restrict__ tbl, float2* __restrict__ st,
                                               float* __restrict__ out){
  const int t = threadIdx.x;
  const int batch = blockIdx.x >> 4, o = blockIdx.x & 15;
  const unsigned bb = (unsigned)batch<<16;
  const unsigned ohi = ((unsigned)(o&1)<<8) | ((unsigned)(o&2)<<9) | ((unsigned)(o&4)<<10) | ((unsigned)(o&8)<<11);
  __shared__ float2 lds[2][4096];
  float2 a[16];
  const unsigned IbA = (unsigned)t | ohi;
  const unsigned jb0 = (unsigned)(t&1) | ((unsigned)(t&2)<<1) | ((unsigned)(t&4)<<2) | ((unsigned)(t&8)<<3);
  const unsigned IbB = jb0 | (((unsigned)(t>>4)&1u)<<9) | (((unsigned)(t>>5)&1u)<<11)
                           | (((unsigned)(t>>6)&1u)<<13) | (((unsigned)(t>>7)&1u)<<15) | ohi;
  // Stage A: load with sigma1 fused; reg = j{8..11} -> g{9,11,13,15}
  #pragma unroll
  for (int r=0;r<16;r++){
    unsigned Il = (unsigned)t | ohi | ((unsigned)(r&1)<<9) | ((unsigned)(r&2)<<10)
                                    | ((unsigned)(r&4)<<11) | ((unsigned)(r&8)<<12);
    unsigned s1 = Il ^ ((Il & 0xAAAAu) >> 1);   // pool-1 CNOT permutation
    a[r] = st[bb | s1];
  }
  gate<0>(a, tbl+35*8); gate<1>(a, tbl+34*8); gate<2>(a, tbl+33*8); gate<3>(a, tbl+32*8); // L2d0 hi
  #pragma unroll
  for (int r=0;r<16;r++){ int j = t | (r<<8); lds[0][swz(j)] = a[r]; }
  __syncthreads();
  // Stage B: reg = j{1,3,5,7} -> g{1,3,5,7}
  #pragma unroll
  for (int r=0;r<16;r++){
    int j = (t&1) | ((r&1)<<1) | ((t&2)<<1) | ((r&2)<<2) | ((t&4)<<2) | ((r&4)<<3)
          | ((t&8)<<3) | ((r&8)<<4) | ((t>>4)<<8);
    a[r] = lds[0][swz(j)];
  }
  gate<0>(a, tbl+39*8); gate<1>(a, tbl+38*8); gate<2>(a, tbl+37*8); gate<3>(a, tbl+36*8); // L2d0 lo
  diag<32,8, 2u,8u,32u,128u>(a, tbl, IbB);                                                // D2_0
  gate<0>(a, tbl+47*8); gate<1>(a, tbl+46*8); gate<2>(a, tbl+45*8); gate<3>(a, tbl+44*8); // L2d1 lo
  #pragma unroll
  for (int r=0;r<16;r++){
    int j = (t&1) | ((r&1)<<1) | ((t&2)<<1) | ((r&2)<<2) | ((t&4)<<2) | ((r&4)<<3)
          | ((t&8)<<3) | ((r&8)<<4) | ((t>>4)<<8);
    lds[1][swz(j)] = a[r];
  }
  __syncthreads();
  // Stage C: reg = j{8..11}
  #pragma unroll
  for (int r=0;r<16;r++){ int j = t | (r<<8); a[r] = lds[1][swz(j)]; }
  gate<0>(a, tbl+43*8); gate<1>(a, tbl+42*8); gate<2>(a, tbl+41*8); gate<3>(a, tbl+40*8); // L2d1 hi
  diag<40,8, (1u<<9),(1u<<11),(1u<<13),(1u<<15)>(a, tbl, IbA);                            // D2_1
  cnotg<3,2>(a); cnotg<1,0>(a);                                                           // sigma2 hi
  #pragma unroll
  for (int r=0;r<16;r++){ int j = t | (r<<8); lds[0][swz(j)] = a[r]; }
  __syncthreads();
  // Stage D: reg = j{1,3,5,7}
  #pragma unroll
  for (int r=0;r<16;r++){
    int j = (t&1) | ((r&1)<<1) | ((t&2)<<1) | ((r&2)<<2) | ((t&4)<<2) | ((r&4)<<3)
          | ((t&8)<<3) | ((r&8)<<4) | ((t>>4)<<8);
    a[r] = lds[0][swz(j)];
  }
  cnotg<3,2>(a); cnotg<1,0>(a);                                                           // sigma2 lo
  gate<3>(a, tbl+50*8); gate<1>(a, tbl+51*8);                                             // L3d0 g7,g3
  #pragma unroll
  for (int r=0;r<16;r++){
    int j = (t&1) | ((r&1)<<1) | ((t&2)<<1) | ((r&2)<<2) | ((t&4)<<2) | ((r&4)<<3)
          | ((t&8)<<3) | ((r&8)<<4) | ((t>>4)<<8);
    lds[1][swz(j)] = a[r];
  }
  __syncthreads();
  // Stage E: reg = j{8..11}
  #pragma unroll
  for (int r=0;r<16;r++){ int j = t | (r<<8); a[r] = lds[1][swz(j)]; }
  gate<3>(a, tbl+48*8); gate<1>(a, tbl+49*8);                                             // L3d0 g15,g11
  diag<48,4, (1u<<9),(1u<<11),(1u<<13),(1u<<15)>(a, tbl, IbA);                            // D3_0
  gate<3>(a, tbl+52*8); gate<1>(a, tbl+53*8);                                             // L3d1 g15,g11
  #pragma unroll
  for (int r=0;r<16;r++){ int j = t | (r<<8); lds[0][swz(j)] = a[r]; }
  __syncthreads();
  // Stage F: reg = j{1,3,5,7}
  #pragma unroll
  for (int r=0;r<16;r++){
    int j = (t&1) | ((r&1)<<1) | ((t&2)<<1) | ((r&2)<<2) | ((t&4)<<2) | ((r&4)<<3)
          | ((t&8)<<3) | ((r&8)<<4) | ((t>>4)<<8);
    a[r] = lds[0][swz(j)];
  }
  gate<3>(a, tbl+54*8); gate<1>(a, tbl+55*8);                                             // L3d1 g7,g3
  diag<52,4, 2u,8u,32u,128u>(a, tbl, IbB);                                                // D3_1
  cnotg<3,1>(a);                                                                          // sigma3 (7,3)
  gate<3>(a, tbl+57*8);                                                                   // L4d0 g7
  #pragma unroll
  for (int r=0;r<16;r++){
    int j = (t&1) | ((r&1)<<1) | ((t&2)<<1) | ((r&2)<<2) | ((t&4)<<2) | ((r&4)<<3)
          | ((t&8)<<3) | ((r&8)<<4) | ((t>>4)<<8);
    lds[1][swz(j)] = a[r];
  }
  __syncthreads();
  // Stage G: reg = j{8..11}
  #pragma unroll
  for (int r=0;r<16;r++){ int j = t | (r<<8); a[r] = lds[1][swz(j)]; }
  cnotg<3,1>(a);                                                                          // sigma3 (15,11)
  gate<3>(a, tbl+56*8);                                                                   // L4d0 g15
  diag<56,2, (1u<<9),(1u<<11),(1u<<13),(1u<<15)>(a, tbl, IbA);                            // D4_0
  gate<3>(a, tbl+58*8);                                                                   // L4d1 g15
  // sigma4, D4_1, L4d1(g7) dropped: output-invariant (permute/phase/unitary within bit15 groups).
  // Measure Z on bit15 (= slot bit 3):
  float s = 0.f;
  #pragma unroll
  for (int r=0;r<16;r++){
    float w = a[r].x*a[r].x + a[r].y*a[r].y;
    s += (r & 8) ? -w : w;
  }
  #pragma unroll
  for (int off=32; off>0; off>>=1) s += __shfl_down(s, off);
  float* red = reinterpret_cast<float*>(lds);
  if ((t & 63) == 0) red[t>>6] = s;
  __syncthreads();
  if (t == 0) atomicAdd(out + batch, red[0]+red[1]+red[2]+red[3]);
}

extern "C" void kernel_launch(void* const* d_in, const int* in_sizes, int n_in,
                              void* d_out, int out_size, void* d_ws, size_t ws_size,
                              hipStream_t stream) {
  const float* xre = (const float*)d_in[0];
  const float* xim = (const float*)d_in[1];
  const float* p0  = (const float*)d_in[2];
  const float* p1  = (const float*)d_in[3];
  const float* p2  = (const float*)d_in[4];
  const float* p3  = (const float*)d_in[5];
  float* out = (float*)d_out;
  float* tbl = (float*)d_ws;
  float2* st = (float2*)((char*)d_ws + 16384);   // needs 16 KB + 8 MB of workspace

  hipMemsetAsync(d_out, 0, 16*sizeof(float), stream);
  k_setup<<<1, 64, 0, stream>>>(p0, p1, p2, p3, tbl);
  k_pass1<<<256, 256, 0, stream>>>(xre, xim, tbl, st);
  k_pass2<<<256, 256, 0, stream>>>(tbl, st);
  k_pass3<<<256, 256, 0, stream>>>(tbl, st);
  k_pass4<<<256, 256, 0, stream>>>(tbl, st, out);
}

// Round 2
// 122.778 us; speedup vs baseline: 1.0534x; 1.0534x over previous
//
#include <hip/hip_runtime.h>

// Quantum conv circuit, 16 qubits, batch 16.
// Round 2: 8 amps/thread (3 reg bits), 128-thread blocks, 1024 blocks
//   -> 8 waves/CU (2/SIMD) for 2x latency hiding vs round 1's 1 wave/SIMD.
// State: float2[16][65536] in d_ws at offset 16 KB (needs 16 KB + 8 MB workspace).
// Bit convention: wire w <-> flat-index bit p = 15-w.
// Gate table: 60 gates x 8 floats at tbl[0]; couplings (cos,sin) at tbl[480+2k].
// Gate index: L1d0(p)=15-p, L1d1(p)=16+(15-p), L2d0(p)=32+(15-p)/2, L2d1(p)=40+(15-p)/2,
//             L3d0(p)=48+(15-p)/4, L3d1(p)=52+(15-p)/4, L4d0(p)=56+(15-p)/8, L4d1(p)=58+(15-p)/8.

#define DEV __device__ __forceinline__
#define TB(i) (tbl + (i)*8)

__device__ static const unsigned char G_CP[60] = {
  15,14,13,12,11,10,9,8,7,6,5,4,3,2,1,0,
  15,14,13,12,11,10,9,8,7,6,5,4,3,2,1,0,
  15,13,11,9,7,5,3,1,
  15,13,11,9,7,5,3,1,
  15,11,7,3,
  15,11,7,3,
  15,7,
  15,7
};
__device__ static const unsigned char G_CQ[60] = {
  14,13,12,11,10,9,8,7,6,5,4,3,2,1,0,15,
  14,13,12,11,10,9,8,7,6,5,4,3,2,1,0,15,
  13,11,9,7,5,3,1,15,
  13,11,9,7,5,3,1,15,
  11,7,3,15,
  11,7,3,15,
  7,15,
  7,15
};

DEV float2 F2(float x, float y){ float2 r; r.x = x; r.y = y; return r; }
DEV float2 cmulf(float2 a, float2 b){ return F2(a.x*b.x - a.y*b.y, a.x*b.y + a.y*b.x); }
// XOR bank swizzle on float2 slot index (32 banks = 16 float2 columns).
// Verified rank-4 (uniform) for every exchange layout used below.
DEV int swz(int j){ return j ^ ((j>>4)&15) ^ ((j>>6)&15); }

// 2x2 unitary on register slot bit B of a[8]. g = {u00r,u00i,u01r,u01i,u10r,u10i,u11r,u11i}.
template<int B>
DEV void gate8(float2* a, const float* __restrict__ g){
  float u00r=g[0],u00i=g[1],u01r=g[2],u01i=g[3],u10r=g[4],u10i=g[5],u11r=g[6],u11i=g[7];
  #pragma unroll
  for (int m=0; m<4; m++){
    int i0 = ((m>>B)<<(B+1)) | (m & ((1<<B)-1));
    int i1 = i0 | (1<<B);
    float2 x0=a[i0], x1=a[i1];
    a[i0] = F2(u00r*x0.x - u00i*x0.y + u01r*x1.x - u01i*x1.y,
               u00r*x0.y + u00i*x0.x + u01r*x1.y + u01i*x1.x);
    a[i1] = F2(u10r*x0.x - u10i*x0.y + u11r*x1.x - u11i*x1.y,
               u10r*x0.y + u10i*x0.x + u11r*x1.y + u11i*x1.x);
  }
}

// CNOT: control slot-bit CB, target slot-bit TB (in-register permutation).
template<int CB,int TB>
DEV void cnot8(float2* a){
  #pragma unroll
  for (int r=0; r<8; r++){
    if ( ((r>>CB)&1)==1 && ((r>>TB)&1)==0 ){
      float2 tmp = a[r]; a[r] = a[r | (1<<TB)]; a[r | (1<<TB)] = tmp;
    }
  }
}

// RZZ diagonal round, couplings [C0,C0+N). Ib = global 16-bit index with reg bits = 0
// (batch excluded; phases are batch-independent). M0..M2 = global masks of slot bits 0..2.
template<int C0,int N,unsigned M0,unsigned M1,unsigned M2>
DEV void diag8(float2* a, const float* __restrict__ tbl, unsigned Ib){
  const unsigned regmask = M0|M1|M2;
  float2 F0 = F2(1.f, 0.f);
  #pragma unroll
  for (int k=0; k<N; k++){
    const int p = G_CP[C0+k], q = G_CQ[C0+k];
    if ( !(((1u<<p)|(1u<<q)) & regmask) ){
      float c = tbl[480 + 2*(C0+k)], s = tbl[481 + 2*(C0+k)];
      unsigned x = ((Ib>>p) ^ (Ib>>q)) & 1u;
      F0 = cmulf(F0, F2(c, x ? s : -s));
    }
  }
  #pragma unroll
  for (int r=0; r<8; r++){
    unsigned Ir = Ib ^ ((r&1)?M0:0u) ^ ((r&2)?M1:0u) ^ ((r&4)?M2:0u);
    float2 ph = F0;
    #pragma unroll
    for (int k=0; k<N; k++){
      const int p = G_CP[C0+k], q = G_CQ[C0+k];
      if ( ((1u<<p)|(1u<<q)) & regmask ){
        float c = tbl[480 + 2*(C0+k)], s = tbl[481 + 2*(C0+k)];
        unsigned x = ((Ir>>p) ^ (Ir>>q)) & 1u;
        ph = cmulf(ph, F2(c, x ? s : -s));
      }
    }
    a[r] = cmulf(a[r], ph);
  }
}

// ---------- setup: U = RX(t2)*RZ(t1)*RX(t0) in double + coupling cos/sin; zero out ----------
__global__ void k_setup(const float* __restrict__ p0, const float* __restrict__ p1,
                        const float* __restrict__ p2, const float* __restrict__ p3,
                        float* __restrict__ tbl, float* __restrict__ out){
  int g = threadIdx.x;
  if (g < 16) out[g] = 0.f;
  if (g >= 60) return;
  int d, j, n; const float* P;
  if (g < 32)      { n=16; d=(g>>4)&1; j=g&15; P=p0; }
  else if (g < 48) { n=8;  d=(g>>3)&1; j=g&7;  P=p1; }
  else if (g < 56) { n=4;  d=(g>>2)&1; j=g&3;  P=p2; }
  else             { n=2;  d=(g>>1)&1; j=g&1;  P=p3; }
  int base = 4*j + 4*n*d;
  double th0 = P[base+0], th1 = P[base+1], th2 = P[base+2], th3 = P[base+3];
  double c0 = cos(th0*0.5), s0 = sin(th0*0.5);
  double ca = cos(th1*0.5), sa = sin(th1*0.5);
  double c2 = cos(th2*0.5), s2 = sin(th2*0.5);
  double B00r =  ca*c0, B00i = -sa*c0;
  double B01r = -sa*s0, B01i = -ca*s0;
  double B10r =  sa*s0, B10i = -ca*s0;
  double B11r =  ca*c0, B11i =  sa*c0;
  double U00r = c2*B00r + s2*B10i, U00i = c2*B00i - s2*B10r;
  double U01r = c2*B01r + s2*B11i, U01i = c2*B01i - s2*B11r;
  double U10r = s2*B00i + c2*B10r, U10i = -s2*B00r + c2*B10i;
  double U11r = s2*B01i + c2*B11r, U11i = -s2*B01r + c2*B11i;
  float* o = tbl + g*8;
  o[0]=(float)U00r; o[1]=(float)U00i; o[2]=(float)U01r; o[3]=(float)U01i;
  o[4]=(float)U10r; o[5]=(float)U10i; o[6]=(float)U11r; o[7]=(float)U11i;
  tbl[480 + 2*g] = (float)cos(th3*0.5);
  tbl[481 + 2*g] = (float)sin(th3*0.5);
}

// ======== pass 1: L1d0 on g0..g9. inner j = g0..9, outer o(6b) = g10..15 ========
__global__ __launch_bounds__(128) void k_pass1(const float* __restrict__ xre, const float* __restrict__ xim,
                                               const float* __restrict__ tbl, float2* __restrict__ st){
  const int t = threadIdx.x;
  const int batch = blockIdx.x >> 6, o = blockIdx.x & 63;
  const unsigned hi = ((unsigned)batch<<16) | ((unsigned)o<<10);
  __shared__ float2 lds[2][1024];
  float2 a[8];
  // A: reg = j{0,1,2}; j = r | (t<<3)
  {
    unsigned base = hi | ((unsigned)t<<3);
    float4 r0 = *(const float4*)(xre+base), r1 = *(const float4*)(xre+base+4);
    float4 i0 = *(const float4*)(xim+base), i1 = *(const float4*)(xim+base+4);
    a[0]=F2(r0.x,i0.x); a[1]=F2(r0.y,i0.y); a[2]=F2(r0.z,i0.z); a[3]=F2(r0.w,i0.w);
    a[4]=F2(r1.x,i1.x); a[5]=F2(r1.y,i1.y); a[6]=F2(r1.z,i1.z); a[7]=F2(r1.w,i1.w);
  }
  gate8<0>(a, TB(15)); gate8<1>(a, TB(14)); gate8<2>(a, TB(13));
  #pragma unroll
  for (int r=0;r<8;r++) lds[0][swz(r | (t<<3))] = a[r];
  __syncthreads();
  // B: reg = j{3,4,5}; j = (t&7) | (r<<3) | ((t>>3)<<6)
  #pragma unroll
  for (int r=0;r<8;r++) a[r] = lds[0][swz((t&7) | (r<<3) | ((t>>3)<<6))];
  gate8<0>(a, TB(12)); gate8<1>(a, TB(11)); gate8<2>(a, TB(10));
  #pragma unroll
  for (int r=0;r<8;r++) lds[1][swz((t&7) | (r<<3) | ((t>>3)<<6))] = a[r];
  __syncthreads();
  // C: reg = j{6,7,8}; j = (t&63) | (r<<6) | ((t>>6)<<9)
  #pragma unroll
  for (int r=0;r<8;r++) a[r] = lds[1][swz((t&63) | (r<<6) | ((t>>6)<<9))];
  gate8<0>(a, TB(9)); gate8<1>(a, TB(8)); gate8<2>(a, TB(7));
  #pragma unroll
  for (int r=0;r<8;r++) lds[0][swz((t&63) | (r<<6) | ((t>>6)<<9))] = a[r];
  __syncthreads();
  // D: reg = j{7,8,9}; j = t | (r<<7)
  #pragma unroll
  for (int r=0;r<8;r++) a[r] = lds[0][swz(t | (r<<7))];
  gate8<2>(a, TB(6));  // g9
  #pragma unroll
  for (int r=0;r<8;r++) st[hi | (unsigned)(t | (r<<7))] = a[r];
}

// ======== pass 2: L1d0 g10..15, D0, L1d1 on {g0..3, g10..15}. outer o(6b) = g4..9 ========
DEV unsigned p2I(int j, int o){ return (unsigned)((j&15) | (o<<4) | ((j>>4)<<10)); }

__global__ __launch_bounds__(128) void k_pass2(const float* __restrict__ tbl, float2* __restrict__ st){
  const int t = threadIdx.x;
  const int batch = blockIdx.x >> 6, o = blockIdx.x & 63;
  const unsigned bb = (unsigned)batch<<16;
  __shared__ float2 lds[2][1024];
  float2 a[8];
  // A: reg = j{7,8,9} = g{13,14,15}; j = t | (r<<7)
  #pragma unroll
  for (int r=0;r<8;r++) a[r] = st[bb | p2I(t | (r<<7), o)];
  gate8<0>(a, TB(2)); gate8<1>(a, TB(1)); gate8<2>(a, TB(0));
  #pragma unroll
  for (int r=0;r<8;r++) lds[0][swz(t | (r<<7))] = a[r];
  __syncthreads();
  // B: reg = j{4,5,6} = g{10,11,12}; j = (t&15) | (r<<4) | ((t>>4)<<7)
  #pragma unroll
  for (int r=0;r<8;r++) a[r] = lds[0][swz((t&15) | (r<<4) | ((t>>4)<<7))];
  gate8<0>(a, TB(5)); gate8<1>(a, TB(4)); gate8<2>(a, TB(3));     // L1d0 g10,g11,g12
  diag8<0,16, (1u<<10),(1u<<11),(1u<<12)>(a, tbl, p2I((t&15) | ((t>>4)<<7), o));  // D0
  gate8<0>(a, TB(21)); gate8<1>(a, TB(20)); gate8<2>(a, TB(19));  // L1d1 g10,g11,g12
  #pragma unroll
  for (int r=0;r<8;r++) lds[1][swz((t&15) | (r<<4) | ((t>>4)<<7))] = a[r];
  __syncthreads();
  // C: reg = j{7,8,9} = g{13,14,15}
  #pragma unroll
  for (int r=0;r<8;r++) a[r] = lds[1][swz(t | (r<<7))];
  gate8<0>(a, TB(18)); gate8<1>(a, TB(17)); gate8<2>(a, TB(16)); // L1d1 g13,g14,g15
  #pragma unroll
  for (int r=0;r<8;r++) lds[0][swz(t | (r<<7))] = a[r];
  __syncthreads();
  // D: reg = j{0,1,2} = g{0,1,2}; j = r | (t<<3)
  #pragma unroll
  for (int r=0;r<8;r++) a[r] = lds[0][swz(r | (t<<3))];
  gate8<0>(a, TB(31)); gate8<1>(a, TB(30)); gate8<2>(a, TB(29)); // L1d1 g0,g1,g2
  #pragma unroll
  for (int r=0;r<8;r++) lds[1][swz(r | (t<<3))] = a[r];
  __syncthreads();
  // E: reg = j{3,4,5}; j = (t&7) | (r<<3) | ((t>>3)<<6)
  #pragma unroll
  for (int r=0;r<8;r++) a[r] = lds[1][swz((t&7) | (r<<3) | ((t>>3)<<6))];
  gate8<0>(a, TB(28));                                           // L1d1 g3
  #pragma unroll
  for (int r=0;r<8;r++) st[bb | p2I((t&7) | (r<<3) | ((t>>3)<<6), o)] = a[r];
}

// ======== pass 3: L1d1 on g4..g9, D1. inner = g0..9, outer o(6b) = g10..15 ========
__global__ __launch_bounds__(128) void k_pass3(const float* __restrict__ tbl, float2* __restrict__ st){
  const int t = threadIdx.x;
  const int batch = blockIdx.x >> 6, o = blockIdx.x & 63;
  const unsigned hi = ((unsigned)batch<<16) | ((unsigned)o<<10);
  __shared__ float2 lds[2][1024];
  float2 a[8];
  // A: reg = j{4,5,6} = g{4,5,6}; j = (t&15) | (r<<4) | ((t>>4)<<7)
  #pragma unroll
  for (int r=0;r<8;r++) a[r] = st[hi | (unsigned)((t&15) | (r<<4) | ((t>>4)<<7))];
  gate8<0>(a, TB(27)); gate8<1>(a, TB(26)); gate8<2>(a, TB(25)); // L1d1 g4,g5,g6
  #pragma unroll
  for (int r=0;r<8;r++) lds[0][swz((t&15) | (r<<4) | ((t>>4)<<7))] = a[r];
  __syncthreads();
  // B: reg = j{7,8,9} = g{7,8,9}; j = t | (r<<7)
  #pragma unroll
  for (int r=0;r<8;r++) a[r] = lds[0][swz(t | (r<<7))];
  gate8<0>(a, TB(24)); gate8<1>(a, TB(23)); gate8<2>(a, TB(22)); // L1d1 g7,g8,g9
  diag8<16,16, (1u<<7),(1u<<8),(1u<<9)>(a, tbl, (unsigned)t | ((unsigned)o<<10)); // D1
  #pragma unroll
  for (int r=0;r<8;r++) st[hi | (unsigned)(t | (r<<7))] = a[r];
}

// ======== pass 4: sigma1(fused gather), L2..L4, measure. ========
// inner j0..9 -> g{0,1,2,3,5,7,9,11,13,15}; outer o(6b) -> g{4,6,8,10,12,14}
DEV unsigned p4I(int j, unsigned og){
  return (unsigned)( (j&15) | (((j>>4)&1)<<5) | (((j>>5)&1)<<7) | (((j>>6)&1)<<9)
                   | (((j>>7)&1)<<11) | (((j>>8)&1)<<13) | (((j>>9)&1)<<15) ) | og;
}
DEV int p4_jA(int t,int r){ return t | (r<<7); }                                   // slots g11,g13,g15 (also E,I)
DEV int p4_jB(int t,int r){ return (t&15) | (r<<4) | ((t>>4)<<7); }                // slots g5,g7,g9
DEV int p4_jC(int t,int r){ return (t&1) | ((r&1)<<1) | (((t>>1)&1)<<2) | (((r>>1)&1)<<3)
                                  | (((t>>2)&1)<<4) | (((r>>2)&1)<<5) | ((t>>3)<<6); } // slots g1,g3,g7 (also H)
DEV int p4_jD(int t,int r){ return (t&15) | ((r&1)<<4) | (((t>>4)&1)<<5) | (((r>>1)&1)<<6)
                                  | (((t>>5)&1)<<7) | (((r>>2)&1)<<8) | ((t>>6)<<9); } // slots g5,g9,g13
DEV int p4_jF(int t,int r){ return (t&63) | ((r&1)<<6) | (((r>>1)&1)<<7) | (((t>>6)&1)<<8) | ((r>>2)<<9); } // g9,g11,g15
DEV int p4_jG(int t,int r){ return (t&15) | ((r&3)<<4) | (((t>>4)&7)<<6) | ((r>>2)<<9); } // slots g5,g7,g15
DEV int p4_jJ(int t,int r){ return (t&7) | ((r&1)<<3) | (((t>>3)&1)<<4) | (((r>>1)&1)<<5)
                                  | (((t>>4)&7)<<6) | ((r>>2)<<9); }               // slots g3,g7,g15

__global__ __launch_bounds__(128) void k_pass4(const float* __restrict__ tbl, float2* __restrict__ st,
                                               float* __restrict__ out){
  const int t = threadIdx.x;
  const int batch = blockIdx.x >> 6, o = blockIdx.x & 63;
  const unsigned bb = (unsigned)batch<<16;
  const unsigned og = ((unsigned)(o&1)<<4) | ((unsigned)(o&2)<<5) | ((unsigned)(o&4)<<6)
                    | ((unsigned)(o&8)<<7) | ((unsigned)(o&16)<<8) | ((unsigned)(o&32)<<9);
  __shared__ float2 lds[2][1024];
  float2 a[8];
  // A: sigma1-fused gather; slots = g{11,13,15}
  #pragma unroll
  for (int r=0;r<8;r++){
    unsigned I = p4I(p4_jA(t,r), og);
    unsigned s1 = I ^ ((I & 0xAAAAu) >> 1);    // pool-1 CNOT permutation (involution)
    a[r] = st[bb | s1];
  }
  gate8<0>(a, TB(34)); gate8<1>(a, TB(33)); gate8<2>(a, TB(32)); // L2d0 g11,g13,g15
  #pragma unroll
  for (int r=0;r<8;r++) lds[0][swz(p4_jA(t,r))] = a[r];
  __syncthreads();
  // B: slots g{5,7,9}
  #pragma unroll
  for (int r=0;r<8;r++) a[r] = lds[0][swz(p4_jB(t,r))];
  gate8<0>(a, TB(37)); gate8<1>(a, TB(36)); gate8<2>(a, TB(35)); // L2d0 g5,g7,g9
  #pragma unroll
  for (int r=0;r<8;r++) lds[1][swz(p4_jB(t,r))] = a[r];
  __syncthreads();
  // C: slots g{1,3,7}
  #pragma unroll
  for (int r=0;r<8;r++) a[r] = lds[1][swz(p4_jC(t,r))];
  gate8<0>(a, TB(39)); gate8<1>(a, TB(38));                      // L2d0 g1,g3 -> all L2d0 done
  diag8<32,8, 2u,8u,128u>(a, tbl, p4I(p4_jC(t,0), og));          // D2_0
  gate8<0>(a, TB(47)); gate8<1>(a, TB(46)); gate8<2>(a, TB(44)); // L2d1 g1,g3,g7
  #pragma unroll
  for (int r=0;r<8;r++) lds[0][swz(p4_jC(t,r))] = a[r];
  __syncthreads();
  // D: slots g{5,9,13}
  #pragma unroll
  for (int r=0;r<8;r++) a[r] = lds[0][swz(p4_jD(t,r))];
  gate8<0>(a, TB(45)); gate8<1>(a, TB(43)); gate8<2>(a, TB(41)); // L2d1 g5,g9,g13
  #pragma unroll
  for (int r=0;r<8;r++) lds[1][swz(p4_jD(t,r))] = a[r];
  __syncthreads();
  // E: slots g{11,13,15}
  #pragma unroll
  for (int r=0;r<8;r++) a[r] = lds[1][swz(p4_jA(t,r))];
  gate8<0>(a, TB(42)); gate8<2>(a, TB(40));                      // L2d1 g11,g15 -> all L2d1 done
  diag8<40,8, (1u<<11),(1u<<13),(1u<<15)>(a, tbl, p4I(p4_jA(t,0), og)); // D2_1
  cnot8<2,1>(a);                                                 // sigma2: CNOT(g15->g13)
  gate8<2>(a, TB(48));                                           // L3d0 g15
  #pragma unroll
  for (int r=0;r<8;r++) lds[0][swz(p4_jA(t,r))] = a[r];
  __syncthreads();
  // F: slots g{9,11,15}
  #pragma unroll
  for (int r=0;r<8;r++) a[r] = lds[0][swz(p4_jF(t,r))];
  cnot8<1,0>(a);                                                 // sigma2: CNOT(g11->g9)
  gate8<1>(a, TB(49));                                           // L3d0 g11
  #pragma unroll
  for (int r=0;r<8;r++) lds[1][swz(p4_jF(t,r))] = a[r];
  __syncthreads();
  // G: slots g{5,7,15}
  #pragma unroll
  for (int r=0;r<8;r++) a[r] = lds[1][swz(p4_jG(t,r))];
  cnot8<1,0>(a);                                                 // sigma2: CNOT(g7->g5)
  gate8<1>(a, TB(50));                                           // L3d0 g7
  #pragma unroll
  for (int r=0;r<8;r++) lds[0][swz(p4_jG(t,r))] = a[r];
  __syncthreads();
  // H: slots g{1,3,7}
  #pragma unroll
  for (int r=0;r<8;r++) a[r] = lds[0][swz(p4_jC(t,r))];
  cnot8<1,0>(a);                                                 // sigma2: CNOT(g3->g1) -> sigma2 done
  gate8<1>(a, TB(51));                                           // L3d0 g3 -> all L3d0 done
  diag8<48,4, 2u,8u,128u>(a, tbl, p4I(p4_jC(t,0), og));          // D3_0
  gate8<1>(a, TB(55)); gate8<2>(a, TB(54));                      // L3d1 g3,g7
  #pragma unroll
  for (int r=0;r<8;r++) lds[1][swz(p4_jC(t,r))] = a[r];
  __syncthreads();
  // I: slots g{11,13,15}
  #pragma unroll
  for (int r=0;r<8;r++) a[r] = lds[1][swz(p4_jA(t,r))];
  gate8<0>(a, TB(53)); gate8<2>(a, TB(52));                      // L3d1 g11,g15 -> all L3d1 done
  diag8<52,4, (1u<<11),(1u<<13),(1u<<15)>(a, tbl, p4I(p4_jA(t,0), og)); // D3_1
  cnot8<2,0>(a);                                                 // sigma3: CNOT(g15->g11)
  gate8<2>(a, TB(56));                                           // L4d0 g15
  #pragma unroll
  for (int r=0;r<8;r++) lds[0][swz(p4_jA(t,r))] = a[r];
  __syncthreads();
  // J: slots g{3,7,15}
  #pragma unroll
  for (int r=0;r<8;r++) a[r] = lds[0][swz(p4_jJ(t,r))];
  cnot8<1,0>(a);                                                 // sigma3: CNOT(g7->g3) -> sigma3 done
  gate8<1>(a, TB(57));                                           // L4d0 g7 -> all L4d0 done
  diag8<56,2, 8u,128u,(1u<<15)>(a, tbl, p4I(p4_jJ(t,0), og));    // D4_0
  gate8<2>(a, TB(58));                                           // L4d1 g15
  // sigma4, D4_1, L4d1(g7) dropped: invariant for the g15 marginal (permute-within-g15 /
  // diagonal-phase / unitary-on-g7 respectively).
  // Measure Z on g15 (= slot bit 2):
  float s = 0.f;
  #pragma unroll
  for (int r=0;r<8;r++){
    float w = a[r].x*a[r].x + a[r].y*a[r].y;
    s += (r & 4) ? -w : w;
  }
  #pragma unroll
  for (int off=32; off>0; off>>=1) s += __shfl_down(s, off);
  __syncthreads();                       // all lanes done reading lds before reuse
  float* red = reinterpret_cast<float*>(lds);
  if ((t & 63) == 0) red[t>>6] = s;
  __syncthreads();
  if (t == 0) atomicAdd(out + batch, red[0] + red[1]);
}

extern "C" void kernel_launch(void* const* d_in, const int* in_sizes, int n_in,
                              void* d_out, int out_size, void* d_ws, size_t ws_size,
                              hipStream_t stream) {
  const float* xre = (const float*)d_in[0];
  const float* xim = (const float*)d_in[1];
  const float* p0  = (const float*)d_in[2];
  const float* p1  = (const float*)d_in[3];
  const float* p2  = (const float*)d_in[4];
  const float* p3  = (const float*)d_in[5];
  float* out = (float*)d_out;
  float* tbl = (float*)d_ws;
  float2* st = (float2*)((char*)d_ws + 16384);   // 16 KB tables + 8 MB state

  k_setup<<<1, 64, 0, stream>>>(p0, p1, p2, p3, tbl, out);
  k_pass1<<<1024, 128, 0, stream>>>(xre, xim, tbl, st);
  k_pass2<<<1024, 128, 0, stream>>>(tbl, st);
  k_pass3<<<1024, 128, 0, stream>>>(tbl, st);
  k_pass4<<<1024, 128, 0, stream>>>(tbl, st, out);
}